// Round 8
// baseline (320.073 us; speedup 1.0000x reference)
//
#include <hip/hip_runtime.h>

#define IN_F 64
#define OUT_F 64
#define WPAD 65   // padded LDS stride (fallback kernels)

// ===========================================================================
// CSR build, rank tier: hist returns per-edge rank -> scatter has NO atomics.
// ===========================================================================

__global__ __launch_bounds__(256) void deg_hist_rank_kernel(
    const int* __restrict__ dst, int* __restrict__ cnt,
    int* __restrict__ rank, int nE)
{
    int i = blockIdx.x * blockDim.x + threadIdx.x;
    int e0 = i * 4;
    if (e0 + 3 < nE) {
        int4 d = *reinterpret_cast<const int4*>(dst + e0);
        int4 r;
        r.x = atomicAdd(cnt + d.x, 1);
        r.y = atomicAdd(cnt + d.y, 1);
        r.z = atomicAdd(cnt + d.z, 1);
        r.w = atomicAdd(cnt + d.w, 1);
        *reinterpret_cast<int4*>(rank + e0) = r;   // coalesced
    } else {
        for (int e = e0; e < nE; ++e) rank[e] = atomicAdd(cnt + dst[e], 1);
    }
}

__global__ __launch_bounds__(256) void deg_hist_kernel(
    const int* __restrict__ dst, int* __restrict__ cnt, int nE)
{
    int i = blockIdx.x * blockDim.x + threadIdx.x;
    int e0 = i * 4;
    if (e0 + 3 < nE) {
        int4 d = *reinterpret_cast<const int4*>(dst + e0);
        atomicAdd(cnt + d.x, 1); atomicAdd(cnt + d.y, 1);
        atomicAdd(cnt + d.z, 1); atomicAdd(cnt + d.w, 1);
    } else {
        for (int e = e0; e < nE; ++e) atomicAdd(cnt + dst[e], 1);
    }
}

__global__ __launch_bounds__(1024) void scan_block_kernel(
    int* __restrict__ c, int* __restrict__ partials, int nN)
{
    __shared__ int buf[1024];
    int t = threadIdx.x;
    int gid = blockIdx.x * 1024 + t;
    int v = (gid < nN) ? c[gid] : 0;
    buf[t] = v;
    __syncthreads();
    for (int off = 1; off < 1024; off <<= 1) {
        int u = (t >= off) ? buf[t - off] : 0;
        __syncthreads();
        buf[t] += u;
        __syncthreads();
    }
    if (gid < nN) c[gid] = buf[t] - v;            // exclusive
    if (t == 1023) partials[blockIdx.x] = buf[t]; // inclusive block total
}

__global__ __launch_bounds__(1024) void scan_partials_kernel(
    int* __restrict__ p, int nP)
{
    __shared__ int buf[1024];
    int t = threadIdx.x;
    int v = (t < nP) ? p[t] : 0;
    buf[t] = v;
    __syncthreads();
    for (int off = 1; off < 1024; off <<= 1) {
        int u = (t >= off) ? buf[t - off] : 0;
        __syncthreads();
        buf[t] += u;
        __syncthreads();
    }
    if (t < nP) p[t] = buf[t] - v;
}

__global__ __launch_bounds__(1024) void scan_add_kernel(
    int* __restrict__ c, const int* __restrict__ p, int nN)
{
    int gid = blockIdx.x * 1024 + threadIdx.x;
    if (gid < nN) c[gid] += p[blockIdx.x];
}

__global__ __launch_bounds__(256) void scatter_rank_kernel(
    const int* __restrict__ src, const int* __restrict__ dst,
    const float* __restrict__ ef, const int* __restrict__ rank,
    const int* __restrict__ offs, int2* __restrict__ csr, int nE)
{
    int i = blockIdx.x * blockDim.x + threadIdx.x;
    int e0 = i * 4;
    if (e0 + 3 < nE) {
        int4   s = *reinterpret_cast<const int4*>(src + e0);
        int4   d = *reinterpret_cast<const int4*>(dst + e0);
        int4   r = *reinterpret_cast<const int4*>(rank + e0);
        float4 w = *reinterpret_cast<const float4*>(ef + e0);
        int p0 = offs[d.x] + r.x;
        int p1 = offs[d.y] + r.y;
        int p2 = offs[d.z] + r.z;
        int p3 = offs[d.w] + r.w;
        csr[p0] = make_int2(s.x, __float_as_int(w.x));
        csr[p1] = make_int2(s.y, __float_as_int(w.y));
        csr[p2] = make_int2(s.z, __float_as_int(w.z));
        csr[p3] = make_int2(s.w, __float_as_int(w.w));
    } else {
        for (int e = e0; e < nE; ++e) {
            int pos = offs[dst[e]] + rank[e];
            csr[pos] = make_int2(src[e], __float_as_int(ef[e]));
        }
    }
}

__global__ __launch_bounds__(256) void scatter_kernel(
    const int* __restrict__ src, const int* __restrict__ dst,
    const float* __restrict__ ef, int* __restrict__ cursor,
    int2* __restrict__ csr, int nE)
{
    int i = blockIdx.x * blockDim.x + threadIdx.x;
    int e0 = i * 4;
    if (e0 + 3 < nE) {
        int4   s = *reinterpret_cast<const int4*>(src + e0);
        int4   d = *reinterpret_cast<const int4*>(dst + e0);
        float4 w = *reinterpret_cast<const float4*>(ef + e0);
        int p0 = atomicAdd(cursor + d.x, 1); csr[p0] = make_int2(s.x, __float_as_int(w.x));
        int p1 = atomicAdd(cursor + d.y, 1); csr[p1] = make_int2(s.y, __float_as_int(w.y));
        int p2 = atomicAdd(cursor + d.z, 1); csr[p2] = make_int2(s.z, __float_as_int(w.z));
        int p3 = atomicAdd(cursor + d.w, 1); csr[p3] = make_int2(s.w, __float_as_int(w.w));
    } else {
        for (int e = e0; e < nE; ++e) {
            int d = dst[e];
            int pos = atomicAdd(cursor + d, 1);
            csr[pos] = make_int2(src[e], __float_as_int(ef[e]));
        }
    }
}

// ===========================================================================
// Phase G: gather+mean. One wave per node, no LDS/weights; VGPR<=64.
// inc_mode: 1 = c[] inclusive ends, 0 = c[] exclusive offsets.
// ===========================================================================
__global__ __launch_bounds__(256, 8) void gather_kernel(
    const float* __restrict__ feat, const int2* __restrict__ csr,
    const int* __restrict__ c, float* __restrict__ hout,
    int nN, int nE, int inc_mode)
{
    int wave = threadIdx.x >> 6, lane = threadIdx.x & 63;
    int n = blockIdx.x * 4 + wave;
    if (n >= nN) return;

    int start, end;
    if (inc_mode) { start = (n == 0) ? 0 : c[n - 1]; end = c[n]; }
    else          { start = c[n]; end = (n + 1 < nN) ? c[n + 1] : nE; }

    int g   = lane >> 4;
    int sub = lane & 15;
    float ax = 0.f, ay = 0.f, az = 0.f, aw = 0.f;

    int e = start + g;
    for (; e + 12 < end; e += 16) {
        int2 p0 = csr[e];
        int2 p1 = csr[e + 4];
        int2 p2 = csr[e + 8];
        int2 p3 = csr[e + 12];
        const float4 v0 = *reinterpret_cast<const float4*>(feat + (size_t)p0.x * IN_F + sub * 4);
        const float4 v1 = *reinterpret_cast<const float4*>(feat + (size_t)p1.x * IN_F + sub * 4);
        const float4 v2 = *reinterpret_cast<const float4*>(feat + (size_t)p2.x * IN_F + sub * 4);
        const float4 v3 = *reinterpret_cast<const float4*>(feat + (size_t)p3.x * IN_F + sub * 4);
        float w0 = __int_as_float(p0.y), w1 = __int_as_float(p1.y);
        float w2 = __int_as_float(p2.y), w3 = __int_as_float(p3.y);
        ax = fmaf(v0.x, w0, ax); ay = fmaf(v0.y, w0, ay);
        az = fmaf(v0.z, w0, az); aw = fmaf(v0.w, w0, aw);
        ax = fmaf(v1.x, w1, ax); ay = fmaf(v1.y, w1, ay);
        az = fmaf(v1.z, w1, az); aw = fmaf(v1.w, w1, aw);
        ax = fmaf(v2.x, w2, ax); ay = fmaf(v2.y, w2, ay);
        az = fmaf(v2.z, w2, az); aw = fmaf(v2.w, w2, aw);
        ax = fmaf(v3.x, w3, ax); ay = fmaf(v3.y, w3, ay);
        az = fmaf(v3.z, w3, az); aw = fmaf(v3.w, w3, aw);
    }
    if (e + 4 < end) {
        int2 p0 = csr[e];
        int2 p1 = csr[e + 4];
        const float4 v0 = *reinterpret_cast<const float4*>(feat + (size_t)p0.x * IN_F + sub * 4);
        const float4 v1 = *reinterpret_cast<const float4*>(feat + (size_t)p1.x * IN_F + sub * 4);
        float w0 = __int_as_float(p0.y), w1 = __int_as_float(p1.y);
        ax = fmaf(v0.x, w0, ax); ay = fmaf(v0.y, w0, ay);
        az = fmaf(v0.z, w0, az); aw = fmaf(v0.w, w0, aw);
        ax = fmaf(v1.x, w1, ax); ay = fmaf(v1.y, w1, ay);
        az = fmaf(v1.z, w1, az); aw = fmaf(v1.w, w1, aw);
        e += 8;
    }
    if (e < end) {
        int2 p = csr[e];
        const float4 v = *reinterpret_cast<const float4*>(feat + (size_t)p.x * IN_F + sub * 4);
        float w = __int_as_float(p.y);
        ax = fmaf(v.x, w, ax); ay = fmaf(v.y, w, ay);
        az = fmaf(v.z, w, az); aw = fmaf(v.w, w, aw);
    }

    ax += __shfl_xor(ax, 16); ax += __shfl_xor(ax, 32);
    ay += __shfl_xor(ay, 16); ay += __shfl_xor(ay, 32);
    az += __shfl_xor(az, 16); az += __shfl_xor(az, 32);
    aw += __shfl_xor(aw, 16); aw += __shfl_xor(aw, 32);

    float invd = 1.0f / (float)max(end - start, 1);
    if (lane < 16) {
        float4 hv = make_float4(ax * invd, ay * invd, az * invd, aw * invd);
        *reinterpret_cast<float4*>(hout + (size_t)n * IN_F + sub * 4) = hv;
    }
}

// ===========================================================================
// Phase T (lane = node): out[n][:] = feat[n]·Ws^T + h[n]·Wn^T + b, in place.
// Lane owns node n; f/h rows live in 128 VGPRs (static float4[16] arrays).
// Weight rows W[o][:] are wave-uniform -> compiler scalarizes to s_load
// (scalar pipe + K$), so the main loop has ZERO LDS traffic and no broadcast.
// Each lane's 16 KB f/h working set is L1-resident; out-row writes cover
// full lines over the o-loop (HBM WRITE stays ~25.6 MB).
// ===========================================================================
__global__ __launch_bounds__(64) void transform_nl_kernel(
    const float* __restrict__ feat,
    const float* __restrict__ W_self, const float* __restrict__ b_self,
    const float* __restrict__ W_neigh, const float* __restrict__ b_neigh,
    float* __restrict__ out, int nN)
{
    int n = blockIdx.x * 64 + threadIdx.x;
    bool active = (n < nN);
    size_t row = (size_t)(active ? n : 0) * IN_F;   // clamp: inactive lanes read row 0

    const float4* fp = reinterpret_cast<const float4*>(feat + row);
    const float4* hp = reinterpret_cast<const float4*>(out + row);
    float4 f[16], h[16];
    #pragma unroll
    for (int i = 0; i < 16; ++i) { f[i] = fp[i]; h[i] = hp[i]; }

    float4* op = reinterpret_cast<float4*>(out + row);
    #pragma unroll 1
    for (int og = 0; og < 16; ++og) {
        float r[4];
        #pragma unroll
        for (int c = 0; c < 4; ++c) {
            int o = og * 4 + c;
            const float* __restrict__ ws = W_self + o * IN_F;   // uniform -> s_load
            const float* __restrict__ wn = W_neigh + o * IN_F;  // uniform -> s_load
            float a0 = b_self[o] + b_neigh[o], a1 = 0.f;
            #pragma unroll
            for (int i = 0; i < 16; ++i) {
                a0 = fmaf(f[i].x, ws[4 * i + 0], a0);
                a1 = fmaf(f[i].y, ws[4 * i + 1], a1);
                a0 = fmaf(f[i].z, ws[4 * i + 2], a0);
                a1 = fmaf(f[i].w, ws[4 * i + 3], a1);
                a0 = fmaf(h[i].x, wn[4 * i + 0], a0);
                a1 = fmaf(h[i].y, wn[4 * i + 1], a1);
                a0 = fmaf(h[i].z, wn[4 * i + 2], a0);
                a1 = fmaf(h[i].w, wn[4 * i + 3], a1);
            }
            r[c] = a0 + a1;
        }
        if (active) op[og] = make_float4(r[0], r[1], r[2], r[3]);
    }
}

// ===========================================================================
// Last-resort fallback (tiny ws): atomic edge scatter into out.
// ===========================================================================
__global__ __launch_bounds__(256) void edge_scatter_kernel(
    const float* __restrict__ feat, const float* __restrict__ e_feat,
    const int* __restrict__ src, const int* __restrict__ dst,
    float* __restrict__ neigh, int* __restrict__ deg, int nE)
{
    int t = blockIdx.x * blockDim.x + threadIdx.x;
    int e = t >> 4;
    if (e >= nE) return;
    int sub = t & 15;
    int s = src[e], d = dst[e];
    float w = e_feat[e];
    const float4 v = *reinterpret_cast<const float4*>(feat + (size_t)s * IN_F + sub * 4);
    float* p = neigh + (size_t)d * IN_F + sub * 4;
    atomicAdd(p + 0, v.x * w);
    atomicAdd(p + 1, v.y * w);
    atomicAdd(p + 2, v.z * w);
    atomicAdd(p + 3, v.w * w);
    if (sub == 0) atomicAdd(deg + d, 1);
}

__global__ __launch_bounds__(256) void node_kernel(
    const float* __restrict__ feat,
    const float* __restrict__ W_self, const float* __restrict__ b_self,
    const float* __restrict__ W_neigh, const float* __restrict__ b_neigh,
    const int* __restrict__ deg,
    float* __restrict__ out, int nN)
{
    __shared__ float Ws[IN_F * WPAD];
    __shared__ float Wn[IN_F * WPAD];
    __shared__ float frow[4][IN_F];
    __shared__ float hrow[4][IN_F];
    int tid = threadIdx.x;
    for (int idx = tid; idx < IN_F * OUT_F; idx += 256) {
        int o = idx >> 6, i = idx & 63;
        Ws[i * WPAD + o] = W_self[o * IN_F + i];
        Wn[i * WPAD + o] = W_neigh[o * IN_F + i];
    }
    __syncthreads();
    int wave = tid >> 6, lane = tid & 63;
    int n = blockIdx.x * 4 + wave;
    if (n >= nN) return;
    float f  = feat[(size_t)n * IN_F + lane];
    float ns = out[(size_t)n * IN_F + lane];
    float invd = 1.0f / (float)max(deg[n], 1);
    frow[wave][lane] = f;
    hrow[wave][lane] = ns * invd;
    __builtin_amdgcn_s_waitcnt(0);
    __builtin_amdgcn_wave_barrier();
    float acc = b_self[lane] + b_neigh[lane];
    #pragma unroll
    for (int i = 0; i < IN_F; ++i) {
        acc = fmaf(frow[wave][i], Ws[i * WPAD + lane], acc);
        acc = fmaf(hrow[wave][i], Wn[i * WPAD + lane], acc);
    }
    out[(size_t)n * IN_F + lane] = acc;
}

extern "C" void kernel_launch(void* const* d_in, const int* in_sizes, int n_in,
                              void* d_out, int out_size, void* d_ws, size_t ws_size,
                              hipStream_t stream) {
    const float* feat    = (const float*)d_in[0];
    const float* e_feat  = (const float*)d_in[1];
    const int*   src     = (const int*)d_in[2];
    const int*   dst     = (const int*)d_in[3];
    const float* W_self  = (const float*)d_in[4];
    const float* b_self  = (const float*)d_in[5];
    const float* W_neigh = (const float*)d_in[6];
    const float* b_neigh = (const float*)d_in[7];

    int nN = in_sizes[0] / IN_F;    // 100000
    int nE = in_sizes[2];           // 1600000

    float* out = (float*)d_out;

    size_t offs_b = ((size_t)nN * sizeof(int) + 15) & ~(size_t)15;
    size_t rank_b = ((size_t)nE * sizeof(int) + 15) & ~(size_t)15;
    size_t csr_b  = (size_t)nE * sizeof(int2);

    int nB  = (nN + 1023) / 1024;
    int nT4 = (nE + 3) / 4;
    int nTB = (nN + 63) / 64;       // transform blocks (1 wave each)

    if (ws_size >= offs_b + rank_b + csr_b) {
        // ---- rank tier: atomic-free scatter ----
        int*  offs = (int*)d_ws;
        int*  rank = (int*)((char*)d_ws + offs_b);
        int2* csr  = (int2*)((char*)d_ws + offs_b + rank_b);
        int*  partials = (int*)csr;   // alias: used only BEFORE csr is written

        hipMemsetAsync(offs, 0, (size_t)nN * sizeof(int), stream);
        deg_hist_rank_kernel<<<(nT4 + 255) / 256, 256, 0, stream>>>(dst, offs, rank, nE);
        scan_block_kernel<<<nB, 1024, 0, stream>>>(offs, partials, nN);
        scan_partials_kernel<<<1, 1024, 0, stream>>>(partials, nB);
        scan_add_kernel<<<nB, 1024, 0, stream>>>(offs, partials, nN);
        scatter_rank_kernel<<<(nT4 + 255) / 256, 256, 0, stream>>>(
            src, dst, e_feat, rank, offs, csr, nE);
        gather_kernel<<<(nN + 3) / 4, 256, 0, stream>>>(feat, csr, offs, out,
                                                        nN, nE, 0);
        transform_nl_kernel<<<nTB, 64, 0, stream>>>(
            feat, W_self, b_self, W_neigh, b_neigh, out, nN);
    } else if (ws_size >= offs_b + csr_b) {
        // ---- mid tier: atomic scatter ----
        int*  cursor = (int*)d_ws;
        int2* csr    = (int2*)((char*)d_ws + offs_b);
        int*  partials = (int*)csr;

        hipMemsetAsync(cursor, 0, (size_t)nN * sizeof(int), stream);
        deg_hist_kernel<<<(nT4 + 255) / 256, 256, 0, stream>>>(dst, cursor, nE);
        scan_block_kernel<<<nB, 1024, 0, stream>>>(cursor, partials, nN);
        scan_partials_kernel<<<1, 1024, 0, stream>>>(partials, nB);
        scan_add_kernel<<<nB, 1024, 0, stream>>>(cursor, partials, nN);
        scatter_kernel<<<(nT4 + 255) / 256, 256, 0, stream>>>(src, dst, e_feat,
                                                              cursor, csr, nE);
        gather_kernel<<<(nN + 3) / 4, 256, 0, stream>>>(feat, csr, cursor, out,
                                                        nN, nE, 1);
        transform_nl_kernel<<<nTB, 64, 0, stream>>>(
            feat, W_self, b_self, W_neigh, b_neigh, out, nN);
    } else {
        // ---- fallback atomic path ----
        int* deg = (int*)d_ws;
        hipMemsetAsync(out, 0, (size_t)nN * OUT_F * sizeof(float), stream);
        hipMemsetAsync(deg, 0, (size_t)nN * sizeof(int), stream);
        long long threads = (long long)nE * 16;
        edge_scatter_kernel<<<(int)((threads + 255) / 256), 256, 0, stream>>>(
            feat, e_feat, src, dst, out, deg, nE);
        node_kernel<<<(nN + 3) / 4, 256, 0, stream>>>(
            feat, W_self, b_self, W_neigh, b_neigh, deg, out, nN);
    }
}

// Round 9
// 222.173 us; speedup vs baseline: 1.4406x; 1.4406x over previous
//
#include <hip/hip_runtime.h>

#define IN_F 64
#define OUT_F 64
#define WPAD 65   // padded LDS stride (fallback kernels)

// ===========================================================================
// CSR build, rank tier: hist returns per-edge rank -> scatter has NO atomics.
// ===========================================================================

__global__ __launch_bounds__(256) void deg_hist_rank_kernel(
    const int* __restrict__ dst, int* __restrict__ cnt,
    int* __restrict__ rank, int nE)
{
    int i = blockIdx.x * blockDim.x + threadIdx.x;
    int e0 = i * 4;
    if (e0 + 3 < nE) {
        int4 d = *reinterpret_cast<const int4*>(dst + e0);
        int4 r;
        r.x = atomicAdd(cnt + d.x, 1);
        r.y = atomicAdd(cnt + d.y, 1);
        r.z = atomicAdd(cnt + d.z, 1);
        r.w = atomicAdd(cnt + d.w, 1);
        *reinterpret_cast<int4*>(rank + e0) = r;   // coalesced
    } else {
        for (int e = e0; e < nE; ++e) rank[e] = atomicAdd(cnt + dst[e], 1);
    }
}

__global__ __launch_bounds__(256) void deg_hist_kernel(
    const int* __restrict__ dst, int* __restrict__ cnt, int nE)
{
    int i = blockIdx.x * blockDim.x + threadIdx.x;
    int e0 = i * 4;
    if (e0 + 3 < nE) {
        int4 d = *reinterpret_cast<const int4*>(dst + e0);
        atomicAdd(cnt + d.x, 1); atomicAdd(cnt + d.y, 1);
        atomicAdd(cnt + d.z, 1); atomicAdd(cnt + d.w, 1);
    } else {
        for (int e = e0; e < nE; ++e) atomicAdd(cnt + dst[e], 1);
    }
}

__global__ __launch_bounds__(1024) void scan_block_kernel(
    int* __restrict__ c, int* __restrict__ partials, int nN)
{
    __shared__ int buf[1024];
    int t = threadIdx.x;
    int gid = blockIdx.x * 1024 + t;
    int v = (gid < nN) ? c[gid] : 0;
    buf[t] = v;
    __syncthreads();
    for (int off = 1; off < 1024; off <<= 1) {
        int u = (t >= off) ? buf[t - off] : 0;
        __syncthreads();
        buf[t] += u;
        __syncthreads();
    }
    if (gid < nN) c[gid] = buf[t] - v;            // exclusive
    if (t == 1023) partials[blockIdx.x] = buf[t]; // inclusive block total
}

__global__ __launch_bounds__(1024) void scan_partials_kernel(
    int* __restrict__ p, int nP)
{
    __shared__ int buf[1024];
    int t = threadIdx.x;
    int v = (t < nP) ? p[t] : 0;
    buf[t] = v;
    __syncthreads();
    for (int off = 1; off < 1024; off <<= 1) {
        int u = (t >= off) ? buf[t - off] : 0;
        __syncthreads();
        buf[t] += u;
        __syncthreads();
    }
    if (t < nP) p[t] = buf[t] - v;
}

__global__ __launch_bounds__(1024) void scan_add_kernel(
    int* __restrict__ c, const int* __restrict__ p, int nN)
{
    int gid = blockIdx.x * 1024 + threadIdx.x;
    if (gid < nN) c[gid] += p[blockIdx.x];
}

__global__ __launch_bounds__(256) void scatter_rank_kernel(
    const int* __restrict__ src, const int* __restrict__ dst,
    const float* __restrict__ ef, const int* __restrict__ rank,
    const int* __restrict__ offs, int2* __restrict__ csr, int nE)
{
    int i = blockIdx.x * blockDim.x + threadIdx.x;
    int e0 = i * 4;
    if (e0 + 3 < nE) {
        int4   s = *reinterpret_cast<const int4*>(src + e0);
        int4   d = *reinterpret_cast<const int4*>(dst + e0);
        int4   r = *reinterpret_cast<const int4*>(rank + e0);
        float4 w = *reinterpret_cast<const float4*>(ef + e0);
        int p0 = offs[d.x] + r.x;
        int p1 = offs[d.y] + r.y;
        int p2 = offs[d.z] + r.z;
        int p3 = offs[d.w] + r.w;
        csr[p0] = make_int2(s.x, __float_as_int(w.x));
        csr[p1] = make_int2(s.y, __float_as_int(w.y));
        csr[p2] = make_int2(s.z, __float_as_int(w.z));
        csr[p3] = make_int2(s.w, __float_as_int(w.w));
    } else {
        for (int e = e0; e < nE; ++e) {
            int pos = offs[dst[e]] + rank[e];
            csr[pos] = make_int2(src[e], __float_as_int(ef[e]));
        }
    }
}

__global__ __launch_bounds__(256) void scatter_kernel(
    const int* __restrict__ src, const int* __restrict__ dst,
    const float* __restrict__ ef, int* __restrict__ cursor,
    int2* __restrict__ csr, int nE)
{
    int i = blockIdx.x * blockDim.x + threadIdx.x;
    int e0 = i * 4;
    if (e0 + 3 < nE) {
        int4   s = *reinterpret_cast<const int4*>(src + e0);
        int4   d = *reinterpret_cast<const int4*>(dst + e0);
        float4 w = *reinterpret_cast<const float4*>(ef + e0);
        int p0 = atomicAdd(cursor + d.x, 1); csr[p0] = make_int2(s.x, __float_as_int(w.x));
        int p1 = atomicAdd(cursor + d.y, 1); csr[p1] = make_int2(s.y, __float_as_int(w.y));
        int p2 = atomicAdd(cursor + d.z, 1); csr[p2] = make_int2(s.z, __float_as_int(w.z));
        int p3 = atomicAdd(cursor + d.w, 1); csr[p3] = make_int2(s.w, __float_as_int(w.w));
    } else {
        for (int e = e0; e < nE; ++e) {
            int d = dst[e];
            int pos = atomicAdd(cursor + d, 1);
            csr[pos] = make_int2(src[e], __float_as_int(ef[e]));
        }
    }
}

// ===========================================================================
// Phase G: gather+mean. One wave per node, no LDS/weights; VGPR<=64.
// inc_mode: 1 = c[] inclusive ends, 0 = c[] exclusive offsets.
// ===========================================================================
__global__ __launch_bounds__(256, 8) void gather_kernel(
    const float* __restrict__ feat, const int2* __restrict__ csr,
    const int* __restrict__ c, float* __restrict__ hout,
    int nN, int nE, int inc_mode)
{
    int wave = threadIdx.x >> 6, lane = threadIdx.x & 63;
    int n = blockIdx.x * 4 + wave;
    if (n >= nN) return;

    int start, end;
    if (inc_mode) { start = (n == 0) ? 0 : c[n - 1]; end = c[n]; }
    else          { start = c[n]; end = (n + 1 < nN) ? c[n + 1] : nE; }

    int g   = lane >> 4;
    int sub = lane & 15;
    float ax = 0.f, ay = 0.f, az = 0.f, aw = 0.f;

    int e = start + g;
    for (; e + 12 < end; e += 16) {
        int2 p0 = csr[e];
        int2 p1 = csr[e + 4];
        int2 p2 = csr[e + 8];
        int2 p3 = csr[e + 12];
        const float4 v0 = *reinterpret_cast<const float4*>(feat + (size_t)p0.x * IN_F + sub * 4);
        const float4 v1 = *reinterpret_cast<const float4*>(feat + (size_t)p1.x * IN_F + sub * 4);
        const float4 v2 = *reinterpret_cast<const float4*>(feat + (size_t)p2.x * IN_F + sub * 4);
        const float4 v3 = *reinterpret_cast<const float4*>(feat + (size_t)p3.x * IN_F + sub * 4);
        float w0 = __int_as_float(p0.y), w1 = __int_as_float(p1.y);
        float w2 = __int_as_float(p2.y), w3 = __int_as_float(p3.y);
        ax = fmaf(v0.x, w0, ax); ay = fmaf(v0.y, w0, ay);
        az = fmaf(v0.z, w0, az); aw = fmaf(v0.w, w0, aw);
        ax = fmaf(v1.x, w1, ax); ay = fmaf(v1.y, w1, ay);
        az = fmaf(v1.z, w1, az); aw = fmaf(v1.w, w1, aw);
        ax = fmaf(v2.x, w2, ax); ay = fmaf(v2.y, w2, ay);
        az = fmaf(v2.z, w2, az); aw = fmaf(v2.w, w2, aw);
        ax = fmaf(v3.x, w3, ax); ay = fmaf(v3.y, w3, ay);
        az = fmaf(v3.z, w3, az); aw = fmaf(v3.w, w3, aw);
    }
    if (e + 4 < end) {
        int2 p0 = csr[e];
        int2 p1 = csr[e + 4];
        const float4 v0 = *reinterpret_cast<const float4*>(feat + (size_t)p0.x * IN_F + sub * 4);
        const float4 v1 = *reinterpret_cast<const float4*>(feat + (size_t)p1.x * IN_F + sub * 4);
        float w0 = __int_as_float(p0.y), w1 = __int_as_float(p1.y);
        ax = fmaf(v0.x, w0, ax); ay = fmaf(v0.y, w0, ay);
        az = fmaf(v0.z, w0, az); aw = fmaf(v0.w, w0, aw);
        ax = fmaf(v1.x, w1, ax); ay = fmaf(v1.y, w1, ay);
        az = fmaf(v1.z, w1, az); aw = fmaf(v1.w, w1, aw);
        e += 8;
    }
    if (e < end) {
        int2 p = csr[e];
        const float4 v = *reinterpret_cast<const float4*>(feat + (size_t)p.x * IN_F + sub * 4);
        float w = __int_as_float(p.y);
        ax = fmaf(v.x, w, ax); ay = fmaf(v.y, w, ay);
        az = fmaf(v.z, w, az); aw = fmaf(v.w, w, aw);
    }

    ax += __shfl_xor(ax, 16); ax += __shfl_xor(ax, 32);
    ay += __shfl_xor(ay, 16); ay += __shfl_xor(ay, 32);
    az += __shfl_xor(az, 16); az += __shfl_xor(az, 32);
    aw += __shfl_xor(aw, 16); aw += __shfl_xor(aw, 32);

    float invd = 1.0f / (float)max(end - start, 1);
    if (lane < 16) {
        float4 hv = make_float4(ax * invd, ay * invd, az * invd, aw * invd);
        *reinterpret_cast<float4*>(hout + (size_t)n * IN_F + sub * 4) = hv;
    }
}

// ===========================================================================
// Phase T (readlane): out[n][o=lane] = f[n]·Ws[lane,:] + h[n]·Wn[lane,:] + b.
// Lane index double-duty: load f/h with lane=i (coalesced), compute with
// lane=o. A-row values broadcast by v_readlane (VALU pipe, zero LDS) —
// replaces round 7's 32 ds_read_b128/node on the CU-shared LDS pipe.
// Weights: per-lane row W[lane][:] in 128 static-indexed VGPRs, loaded once
// per wave from global (L2-hot, one-time). 4 accumulators for FMA ILP.
// ===========================================================================
__global__ __launch_bounds__(256) void transform_rl_kernel(
    const float* __restrict__ feat,
    const float* __restrict__ W_self, const float* __restrict__ b_self,
    const float* __restrict__ W_neigh, const float* __restrict__ b_neigh,
    float* __restrict__ out, int nN, int chunk)
{
    int lane = threadIdx.x & 63;
    int wave = threadIdx.x >> 6;

    // one-time per-lane weight rows (uncoalesced but tiny + L2-hot)
    float wsc[IN_F], wnc[IN_F];
    {
        const float4* wsp = reinterpret_cast<const float4*>(W_self + (size_t)lane * IN_F);
        const float4* wnp = reinterpret_cast<const float4*>(W_neigh + (size_t)lane * IN_F);
        #pragma unroll
        for (int i = 0; i < 16; ++i) {
            float4 a = wsp[i], b = wnp[i];
            wsc[4*i+0] = a.x; wsc[4*i+1] = a.y; wsc[4*i+2] = a.z; wsc[4*i+3] = a.w;
            wnc[4*i+0] = b.x; wnc[4*i+1] = b.y; wnc[4*i+2] = b.z; wnc[4*i+3] = b.w;
        }
    }
    float bias = b_self[lane] + b_neigh[lane];

    int wid = blockIdx.x * 4 + wave;
    int n0 = wid * chunk;
    int n1 = min(n0 + chunk, nN);

    for (int n = n0; n < n1; ++n) {
        float f = feat[(size_t)n * IN_F + lane];   // lane = feature i (coalesced)
        float h = out[(size_t)n * IN_F + lane];
        int fi = __float_as_int(f), hi = __float_as_int(h);

        float a0 = bias, a1 = 0.f, a2 = 0.f, a3 = 0.f;
        #pragma unroll
        for (int i = 0; i < IN_F; i += 2) {        // 128 readlane + 128 FMA
            float f0 = __int_as_float(__builtin_amdgcn_readlane(fi, i));
            float h0 = __int_as_float(__builtin_amdgcn_readlane(hi, i));
            float f1 = __int_as_float(__builtin_amdgcn_readlane(fi, i + 1));
            float h1 = __int_as_float(__builtin_amdgcn_readlane(hi, i + 1));
            a0 = fmaf(f0, wsc[i],     a0);
            a1 = fmaf(h0, wnc[i],     a1);
            a2 = fmaf(f1, wsc[i + 1], a2);
            a3 = fmaf(h1, wnc[i + 1], a3);
        }
        out[(size_t)n * IN_F + lane] = (a0 + a1) + (a2 + a3);  // lane = o (coalesced)
    }
}

// ===========================================================================
// Last-resort fallback (tiny ws): atomic edge scatter into out.
// ===========================================================================
__global__ __launch_bounds__(256) void edge_scatter_kernel(
    const float* __restrict__ feat, const float* __restrict__ e_feat,
    const int* __restrict__ src, const int* __restrict__ dst,
    float* __restrict__ neigh, int* __restrict__ deg, int nE)
{
    int t = blockIdx.x * blockDim.x + threadIdx.x;
    int e = t >> 4;
    if (e >= nE) return;
    int sub = t & 15;
    int s = src[e], d = dst[e];
    float w = e_feat[e];
    const float4 v = *reinterpret_cast<const float4*>(feat + (size_t)s * IN_F + sub * 4);
    float* p = neigh + (size_t)d * IN_F + sub * 4;
    atomicAdd(p + 0, v.x * w);
    atomicAdd(p + 1, v.y * w);
    atomicAdd(p + 2, v.z * w);
    atomicAdd(p + 3, v.w * w);
    if (sub == 0) atomicAdd(deg + d, 1);
}

__global__ __launch_bounds__(256) void node_kernel(
    const float* __restrict__ feat,
    const float* __restrict__ W_self, const float* __restrict__ b_self,
    const float* __restrict__ W_neigh, const float* __restrict__ b_neigh,
    const int* __restrict__ deg,
    float* __restrict__ out, int nN)
{
    __shared__ float Ws[IN_F * WPAD];
    __shared__ float Wn[IN_F * WPAD];
    __shared__ float frow[4][IN_F];
    __shared__ float hrow[4][IN_F];
    int tid = threadIdx.x;
    for (int idx = tid; idx < IN_F * OUT_F; idx += 256) {
        int o = idx >> 6, i = idx & 63;
        Ws[i * WPAD + o] = W_self[o * IN_F + i];
        Wn[i * WPAD + o] = W_neigh[o * IN_F + i];
    }
    __syncthreads();
    int wave = tid >> 6, lane = tid & 63;
    int n = blockIdx.x * 4 + wave;
    if (n >= nN) return;
    float f  = feat[(size_t)n * IN_F + lane];
    float ns = out[(size_t)n * IN_F + lane];
    float invd = 1.0f / (float)max(deg[n], 1);
    frow[wave][lane] = f;
    hrow[wave][lane] = ns * invd;
    __builtin_amdgcn_s_waitcnt(0);
    __builtin_amdgcn_wave_barrier();
    float acc = b_self[lane] + b_neigh[lane];
    #pragma unroll
    for (int i = 0; i < IN_F; ++i) {
        acc = fmaf(frow[wave][i], Ws[i * WPAD + lane], acc);
        acc = fmaf(hrow[wave][i], Wn[i * WPAD + lane], acc);
    }
    out[(size_t)n * IN_F + lane] = acc;
}

extern "C" void kernel_launch(void* const* d_in, const int* in_sizes, int n_in,
                              void* d_out, int out_size, void* d_ws, size_t ws_size,
                              hipStream_t stream) {
    const float* feat    = (const float*)d_in[0];
    const float* e_feat  = (const float*)d_in[1];
    const int*   src     = (const int*)d_in[2];
    const int*   dst     = (const int*)d_in[3];
    const float* W_self  = (const float*)d_in[4];
    const float* b_self  = (const float*)d_in[5];
    const float* W_neigh = (const float*)d_in[6];
    const float* b_neigh = (const float*)d_in[7];

    int nN = in_sizes[0] / IN_F;    // 100000
    int nE = in_sizes[2];           // 1600000

    float* out = (float*)d_out;

    size_t offs_b = ((size_t)nN * sizeof(int) + 15) & ~(size_t)15;
    size_t rank_b = ((size_t)nE * sizeof(int) + 15) & ~(size_t)15;
    size_t csr_b  = (size_t)nE * sizeof(int2);

    int nB  = (nN + 1023) / 1024;
    int nT4 = (nE + 3) / 4;

    // transform: 768 blocks (3/CU) x 4 waves, contiguous chunks
    int tBlocks = 768;
    int tWaves  = tBlocks * 4;
    int tChunk  = (nN + tWaves - 1) / tWaves;   // 33

    if (ws_size >= offs_b + rank_b + csr_b) {
        // ---- rank tier: atomic-free scatter ----
        int*  offs = (int*)d_ws;
        int*  rank = (int*)((char*)d_ws + offs_b);
        int2* csr  = (int2*)((char*)d_ws + offs_b + rank_b);
        int*  partials = (int*)csr;   // alias: used only BEFORE csr is written

        hipMemsetAsync(offs, 0, (size_t)nN * sizeof(int), stream);
        deg_hist_rank_kernel<<<(nT4 + 255) / 256, 256, 0, stream>>>(dst, offs, rank, nE);
        scan_block_kernel<<<nB, 1024, 0, stream>>>(offs, partials, nN);
        scan_partials_kernel<<<1, 1024, 0, stream>>>(partials, nB);
        scan_add_kernel<<<nB, 1024, 0, stream>>>(offs, partials, nN);
        scatter_rank_kernel<<<(nT4 + 255) / 256, 256, 0, stream>>>(
            src, dst, e_feat, rank, offs, csr, nE);
        gather_kernel<<<(nN + 3) / 4, 256, 0, stream>>>(feat, csr, offs, out,
                                                        nN, nE, 0);
        transform_rl_kernel<<<tBlocks, 256, 0, stream>>>(
            feat, W_self, b_self, W_neigh, b_neigh, out, nN, tChunk);
    } else if (ws_size >= offs_b + csr_b) {
        // ---- mid tier: atomic scatter ----
        int*  cursor = (int*)d_ws;
        int2* csr    = (int2*)((char*)d_ws + offs_b);
        int*  partials = (int*)csr;

        hipMemsetAsync(cursor, 0, (size_t)nN * sizeof(int), stream);
        deg_hist_kernel<<<(nT4 + 255) / 256, 256, 0, stream>>>(dst, cursor, nE);
        scan_block_kernel<<<nB, 1024, 0, stream>>>(cursor, partials, nN);
        scan_partials_kernel<<<1, 1024, 0, stream>>>(partials, nB);
        scan_add_kernel<<<nB, 1024, 0, stream>>>(cursor, partials, nN);
        scatter_kernel<<<(nT4 + 255) / 256, 256, 0, stream>>>(src, dst, e_feat,
                                                              cursor, csr, nE);
        gather_kernel<<<(nN + 3) / 4, 256, 0, stream>>>(feat, csr, cursor, out,
                                                        nN, nE, 1);
        transform_rl_kernel<<<tBlocks, 256, 0, stream>>>(
            feat, W_self, b_self, W_neigh, b_neigh, out, nN, tChunk);
    } else {
        // ---- fallback atomic path ----
        int* deg = (int*)d_ws;
        hipMemsetAsync(out, 0, (size_t)nN * OUT_F * sizeof(float), stream);
        hipMemsetAsync(deg, 0, (size_t)nN * sizeof(int), stream);
        long long threads = (long long)nE * 16;
        edge_scatter_kernel<<<(int)((threads + 255) / 256), 256, 0, stream>>>(
            feat, e_feat, src, dst, out, deg, nE);
        node_kernel<<<(nN + 3) / 4, 256, 0, stream>>>(
            feat, W_self, b_self, W_neigh, b_neigh, deg, out, nN);
    }
}